// Round 1
// 300.307 us; speedup vs baseline: 1.0555x; 1.0555x over previous
//
#include <hip/hip_runtime.h>
#include <stdint.h>

// Problem constants: B=32, H=8, N=257, D=64, DIM=512
#define WB_OFF   4210688ull
#define WA_OFF   21119232ull

typedef short short8 __attribute__((ext_vector_type(8)));
typedef float floatx4 __attribute__((ext_vector_type(4)));
typedef __attribute__((address_space(1))) const unsigned int gu32;
typedef __attribute__((address_space(3))) unsigned int lu32;

__device__ __forceinline__ unsigned short f2bf(float f){
  union { float f; uint32_t u; } v; v.f = f;
  uint32_t u = v.u;
  uint32_t r = (u + 0x7FFFu + ((u >> 16) & 1u)) >> 16;  // RNE
  return (unsigned short)r;
}

// ---- JAX Threefry-2x32 ----
__device__ __forceinline__ void threefry(uint32_t k0, uint32_t k1, uint32_t c0, uint32_t c1,
                                         uint32_t& o0, uint32_t& o1){
  const uint32_t ks2 = k0 ^ k1 ^ 0x1BD11BDAu;
  uint32_t x0 = c0 + k0, x1 = c1 + k1;
#define TF_R4(a,b,c,d) \
  x0+=x1; x1=(x1<<(a))|(x1>>(32-(a))); x1^=x0; \
  x0+=x1; x1=(x1<<(b))|(x1>>(32-(b))); x1^=x0; \
  x0+=x1; x1=(x1<<(c))|(x1>>(32-(c))); x1^=x0; \
  x0+=x1; x1=(x1<<(d))|(x1>>(32-(d))); x1^=x0;
  TF_R4(13,15,26,6)  x0+=k1;  x1+=ks2+1u;
  TF_R4(17,29,16,24) x0+=ks2; x1+=k0+2u;
  TF_R4(13,15,26,6)  x0+=k0;  x1+=k1+3u;
  TF_R4(17,29,16,24) x0+=k1;  x1+=ks2+4u;
  TF_R4(13,15,26,6)  x0+=ks2; x1+=k0+5u;
#undef TF_R4
  o0 = x0; o1 = x1;
}

// ---- Kernel A: noise + per-batch mask normalization (partitionable threefry) ----
__global__ __launch_bounds__(256) void prep_kernel(const int* __restrict__ msk,
                                                   float* __restrict__ mnorm){
  const int b = blockIdx.x, p = threadIdx.x;
  const int i = b*256 + p;
  uint32_t A0, A1, B0, B1;
  threefry(0u, 42u, 0u, 0u, A0, A1);   // k1
  threefry(0u, 42u, 0u, 1u, B0, B1);   // k2
  uint32_t h0, h1, l0, l1;
  threefry(A0, A1, 0u, (uint32_t)i, h0, h1);
  threefry(B0, B1, 0u, (uint32_t)i, l0, l1);
  uint32_t hb = h0 ^ h1, lb = l0 ^ l1;
  uint32_t off = ((hb % 127u) * 16u + (lb % 127u)) % 127u;
  int mv = msk[i];
  float m = (mv == 0) ? (float)(1u + off) : (float)mv;
  __shared__ float sm[256];
  sm[p] = m; __syncthreads();
  for (int s = 128; s > 0; s >>= 1){
    if (p < s) sm[p] = fmaxf(sm[p], sm[p+s]);
    __syncthreads();
  }
  mnorm[i] = m / sm[0];
}

// ---- Kernel A2: fp32 -> bf16 convert for x and w ----
__global__ __launch_bounds__(256) void cvt_kernel(const float* __restrict__ x,
                                                  const float* __restrict__ w,
                                                  unsigned short* __restrict__ xb,
                                                  unsigned short* __restrict__ wb){
  int i = blockIdx.x*256 + threadIdx.x;
  if (i < 1052672){
    float4 v = ((const float4*)x)[i];
    ushort4 o; o.x=f2bf(v.x); o.y=f2bf(v.y); o.z=f2bf(v.z); o.w=f2bf(v.w);
    ((ushort4*)xb)[i] = o;
  } else if (i < 1249280){
    int j = i - 1052672;
    float4 v = ((const float4*)w)[j];
    ushort4 o; o.x=f2bf(v.x); o.y=f2bf(v.y); o.z=f2bf(v.z); o.w=f2bf(v.w);
    ((ushort4*)wb)[j] = o;
  }
}

// ---- Kernel B: QKV GEMM  qkv[8224,1536] = xb[8224,512] @ wb[1536,512]^T
// 128x128 tile, BK=64 (8 iters), global_load_lds + XOR col swizzle (conflict-free
// ds_read with unpadded lane-linear LDS). Coalesced C store via LDS. grid(12,65).
__global__ __launch_bounds__(256) void qkv_gemm(const unsigned short* __restrict__ xb,
                                                const unsigned short* __restrict__ wb,
                                                unsigned short* __restrict__ qkv){
  __shared__ unsigned short sm2[128*64*2 + 128*8];  // al/bl 32768B; c_lds [128][136] 34816B
  unsigned short* al = sm2;              // [128][64] lane-linear, col chunks XOR-swizzled
  unsigned short* bl = sm2 + 128*64;
  unsigned short* c_lds = sm2;           // [128][136] (reuse after K-loop)
  const int bn = blockIdx.x, bm = blockIdx.y;
  const int tid = threadIdx.x;
  const int wave = tid >> 6, lane = tid & 63;
  const int l16 = lane & 15, lq = lane >> 4;
  const int wm = (wave & 1) * 64, wn = (wave >> 1) * 64;
  const int row0 = tid >> 3;
  const int ccg = ((tid & 7) ^ (row0 & 7)) * 8;   // swizzled global col chunk
  const int sx = (l16 & 7);                        // compute-side swizzle key
  floatx4 acc[4][4] = {};
  for (int kk = 0; kk < 512; kk += 64){
    #pragma unroll
    for (int p = 0; p < 4; p++){
      int row = p*32 + row0;
      int gm = bm*128 + row; if (gm > 8223) gm = 8223;
      __builtin_amdgcn_global_load_lds((gu32*)&xb[(size_t)gm*512 + kk + ccg],
                                       (lu32*)&al[row*64 + (tid & 7)*8], 16, 0, 0);
      int gn = bn*128 + row;
      __builtin_amdgcn_global_load_lds((gu32*)&wb[(size_t)gn*512 + kk + ccg],
                                       (lu32*)&bl[row*64 + (tid & 7)*8], 16, 0, 0);
    }
    __syncthreads();
    #pragma unroll
    for (int ks = 0; ks < 2; ks++){
      short8 af[4], bf4[4];
      #pragma unroll
      for (int mi = 0; mi < 4; mi++){
        int ch = (ks*4 + lq) ^ sx;
        af[mi] = *(const short8*)&al[(wm + mi*16 + l16)*64 + ch*8];
      }
      #pragma unroll
      for (int ni = 0; ni < 4; ni++){
        int ch = (ks*4 + lq) ^ sx;
        bf4[ni] = *(const short8*)&bl[(wn + ni*16 + l16)*64 + ch*8];
      }
      #pragma unroll
      for (int mi = 0; mi < 4; mi++)
        #pragma unroll
        for (int ni = 0; ni < 4; ni++)
          acc[mi][ni] = __builtin_amdgcn_mfma_f32_16x16x32_bf16(af[mi], bf4[ni], acc[mi][ni], 0, 0, 0);
    }
    __syncthreads();
  }
  // epilogue: C tile -> LDS [128][136] -> coalesced 16B stores
  #pragma unroll
  for (int mi = 0; mi < 4; mi++)
    #pragma unroll
    for (int ni = 0; ni < 4; ni++)
      #pragma unroll
      for (int r = 0; r < 4; r++)
        c_lds[(wm + mi*16 + lq*4 + r)*136 + wn + ni*16 + l16] = f2bf(acc[mi][ni][r]);
  __syncthreads();
  for (int i = tid; i < 128*16; i += 256){
    int row = i >> 4, cc = (i & 15)*8;
    int gm = bm*128 + row;
    if (gm < 8224){
      ushort4 v0 = *(const ushort4*)&c_lds[row*136 + cc];
      ushort4 v1 = *(const ushort4*)&c_lds[row*136 + cc + 4];
      *(ushort4*)&qkv[(size_t)gm*1536 + bn*128 + cc] = v0;
      *(ushort4*)&qkv[(size_t)gm*1536 + bn*128 + cc + 4] = v1;
    }
  }
}

// ---- Kernel C: fused retention. grid(5, 256): x=row tile (64 rows), y=(b*8+h).
// v2 restructure:
//  * phase A: ALL global loads batched to regs first (k, past_kv, mn, q, AND v
//    prefetch), LDS writes after -> one latency wait instead of 16 serialized.
//  * barrier(1) is raw lgkmcnt+s_barrier (no vmcnt drain) so the v prefetch
//    stays in flight across the MFMA + softmax phase (T14).
//  * weights stores go DIRECTLY from acc registers (nontemporal) -> bufw LDS
//    round-trip, half-lane fill loops, and duplicate exp passes deleted.
//  * PV k-loop fully unrolled with wave-uniform guard -> all acc[] indices
//    compile-time (no dynamic ext_vector indexing / scratch risk).
// LDS (dynamic 49440 B), 3 blocks/CU:
//   X [0,39168):   kl[272][72]  ->  vT[64][296]
//   Y [39168,48384): pkl[64][72] ->  plw (per-wave [16][40], 39168+wave*1280)
//   mn [48384,49408), red [49408,49440)
__global__ __launch_bounds__(256, 3) void retention_kernel(
    const unsigned short* __restrict__ qkv,
    const float* __restrict__ past_kv,
    const float* __restrict__ mnorm,
    float* __restrict__ out,
    float* __restrict__ partials){
  const int t  = blockIdx.x;
  const int bh = blockIdx.y;
  const int b = bh >> 3, h = bh & 7;
  const int tid = threadIdx.x;
  const int wave = tid >> 6, lane = tid & 63;
  const int l16 = lane & 15, lq = lane >> 4;
  const int rw = wave * 16;

  extern __shared__ unsigned char smem[];
  unsigned short* kl  = (unsigned short*)smem;                    // [272][72]
  unsigned short* vT  = (unsigned short*)smem;                    // [64][296]
  unsigned short* pkl = (unsigned short*)(smem + 39168);          // [64][72]
  unsigned short* plw = (unsigned short*)(smem + 39168 + wave*1280); // [16][40]
  float* mn  = (float*)(smem + 48384);
  float* red = (float*)(smem + 49408);

  // ---- phase A: zero pads, then one batched global-load burst, then LDS writes
  {
    uint32_t* z = (uint32_t*)(kl + 257*72);
    for (int i = tid; i < 540; i += 256) z[i] = 0;
  }
  ushort4 kreg[17];
  #pragma unroll
  for (int u = 0; u < 17; u++){
    int c = tid + u*256;
    if (c < 4112){
      int row = c >> 4, c4 = (c & 15) * 4;
      kreg[u] = *(const ushort4*)&qkv[(size_t)(b*257 + row)*1536 + 512 + h*64 + c4];
    }
  }
  float4 preg[4];
  #pragma unroll
  for (int u = 0; u < 4; u++){
    int c = tid + u*256;
    int d = c >> 4, e4 = (c & 15) * 4;
    preg[u] = *(const float4*)&past_kv[(size_t)bh*4096 + d*64 + e4];
  }
  float mnv = mnorm[b*256 + tid];
  int giA = t*64 + rw + l16; if (giA > 256) giA = 256;
  short8 aq[2];
  aq[0] = *(const short8*)&qkv[(size_t)(b*257 + giA)*1536 + h*64 + lq*8];
  aq[1] = *(const short8*)&qkv[(size_t)(b*257 + giA)*1536 + h*64 + 32 + lq*8];
  // v prefetch: consumed only after softmax2 -> in flight across the whole
  // compute phase (raw barrier below does not drain vmcnt).
  ushort4 vreg[17];
  #pragma unroll
  for (int u = 0; u < 17; u++){
    int c = tid + u*256;
    if (c < 4112){
      int row = c >> 4, c4 = (c & 15) * 4;
      vreg[u] = *(const ushort4*)&qkv[(size_t)(b*257 + row)*1536 + 1024 + h*64 + c4];
    }
  }
  // LDS writes (counted vmcnt waits: start as soon as kreg/preg land)
  #pragma unroll
  for (int u = 0; u < 17; u++){
    int c = tid + u*256;
    if (c < 4112){
      int row = c >> 4, c4 = (c & 15) * 4;
      *(ushort4*)&kl[row*72 + c4] = kreg[u];
    }
  }
  #pragma unroll
  for (int u = 0; u < 4; u++){
    int c = tid + u*256;
    int d = c >> 4, e4 = (c & 15) * 4;
    pkl[(e4+0)*72 + d] = f2bf(0.125f * preg[u].x);
    pkl[(e4+1)*72 + d] = f2bf(0.125f * preg[u].y);
    pkl[(e4+2)*72 + d] = f2bf(0.125f * preg[u].z);
    pkl[(e4+3)*72 + d] = f2bf(0.125f * preg[u].w);
  }
  mn[tid] = mnv;
  // (1) raw barrier: LDS visibility only; vreg loads stay outstanding
  asm volatile("s_waitcnt lgkmcnt(0)" ::: "memory");
  __builtin_amdgcn_s_barrier();

  // ---- cross-retention: acc2 = q @ (0.125*past_kv)
  floatx4 acc2[4] = {};
  #pragma unroll
  for (int ks = 0; ks < 2; ks++)
    #pragma unroll
    for (int ni = 0; ni < 4; ni++){
      short8 bb = *(const short8*)&pkl[(ni*16 + l16)*72 + ks*32 + lq*8];
      acc2[ni] = __builtin_amdgcn_mfma_f32_16x16x32_bf16(aq[ks], bb, acc2[ni], 0, 0, 0);
    }

  // ---- S = 0.125 * q @ k^T
  floatx4 acc[17] = {};
  #pragma unroll
  for (int ks = 0; ks < 2; ks++)
    #pragma unroll
    for (int c = 0; c < 17; c++){
      short8 bb = *(const short8*)&kl[(c*16 + l16)*72 + ks*32 + lq*8];
      acc[c] = __builtin_amdgcn_mfma_f32_16x16x32_bf16(aq[ks], bb, acc[c], 0, 0, 0);
    }
  #pragma unroll
  for (int c = 0; c < 17; c++) acc[c] *= 0.125f;

  int gi[4]; bool rowok[4];
  #pragma unroll
  for (int r = 0; r < 4; r++){ gi[r] = t*64 + rw + lq*4 + r; rowok[r] = (gi[r] < 257); }

  float mx[4], sum_[4], inv_[4];

  // ================= softmax1 -> weights_before (direct nt stores) =================
  #pragma unroll
  for (int r = 0; r < 4; r++) mx[r] = -3.0e38f;
  #pragma unroll
  for (int c = 0; c < 17; c++){
    bool jok = (c < 16) || (l16 == 0);
    if (jok){
      #pragma unroll
      for (int r = 0; r < 4; r++) mx[r] = fmaxf(mx[r], acc[c][r]);
    }
  }
  #pragma unroll
  for (int m = 1; m < 16; m <<= 1)
    #pragma unroll
    for (int r = 0; r < 4; r++) mx[r] = fmaxf(mx[r], __shfl_xor(mx[r], m, 64));
  #pragma unroll
  for (int r = 0; r < 4; r++) sum_[r] = 0.f;
  #pragma unroll
  for (int c = 0; c < 17; c++){
    bool jok = (c < 16) || (l16 == 0);
    if (jok){
      #pragma unroll
      for (int r = 0; r < 4; r++) sum_[r] += __expf((acc[c][r] - mx[r]) * 0.125f);
    }
  }
  #pragma unroll
  for (int m = 1; m < 16; m <<= 1)
    #pragma unroll
    for (int r = 0; r < 4; r++) sum_[r] += __shfl_xor(sum_[r], m, 64);
  #pragma unroll
  for (int r = 0; r < 4; r++) inv_[r] = 1.0f / sum_[r];

  {
    const size_t gbase = WB_OFF + (size_t)bh*66049;
    #pragma unroll
    for (int r = 0; r < 4; r++){
      size_t rb = gbase + (size_t)gi[r]*257;
      #pragma unroll
      for (int c = 0; c < 17; c++){
        int j = c*16 + l16;
        if (rowok[r] && j < 257){
          float v = __expf((acc[c][r] - mx[r]) * 0.125f) * inv_[r];
          __builtin_nontemporal_store(v, &out[rb + j]);
        }
      }
    }
  }

  // ---- apply mask in registers
  #pragma unroll
  for (int c = 0; c < 17; c++){
    int j = c*16 + l16;
    #pragma unroll
    for (int r = 0; r < 4; r++){
      int ii = gi[r] > 256 ? 256 : gi[r];
      float mv;
      if (j > ii)       mv = 0.f;
      else if (j == ii) mv = 1.f;
      else if (j == 0)  mv = __expf(-5.f * (float)ii * (1.f/256.f));
      else              mv = mn[ii-1] * mn[j-1];
      acc[c][r] *= mv;
    }
  }

  // ================= softmax2 -> weights_after (direct nt stores) =================
  #pragma unroll
  for (int r = 0; r < 4; r++) mx[r] = -3.0e38f;
  #pragma unroll
  for (int c = 0; c < 17; c++){
    bool jok = (c < 16) || (l16 == 0);
    if (jok){
      #pragma unroll
      for (int r = 0; r < 4; r++) mx[r] = fmaxf(mx[r], acc[c][r]);
    }
  }
  #pragma unroll
  for (int m = 1; m < 16; m <<= 1)
    #pragma unroll
    for (int r = 0; r < 4; r++) mx[r] = fmaxf(mx[r], __shfl_xor(mx[r], m, 64));
  #pragma unroll
  for (int r = 0; r < 4; r++) sum_[r] = 0.f;
  #pragma unroll
  for (int c = 0; c < 17; c++){
    bool jok = (c < 16) || (l16 == 0);
    if (jok){
      #pragma unroll
      for (int r = 0; r < 4; r++) sum_[r] += __expf((acc[c][r] - mx[r]) * 0.125f);
    }
  }
  #pragma unroll
  for (int m = 1; m < 16; m <<= 1)
    #pragma unroll
    for (int r = 0; r < 4; r++) sum_[r] += __shfl_xor(sum_[r], m, 64);
  #pragma unroll
  for (int r = 0; r < 4; r++) inv_[r] = 1.0f / sum_[r];

  {
    const size_t gbase = WA_OFF + (size_t)bh*66049;
    #pragma unroll
    for (int r = 0; r < 4; r++){
      size_t rb = gbase + (size_t)gi[r]*257;
      #pragma unroll
      for (int c = 0; c < 17; c++){
        int j = c*16 + l16;
        if (rowok[r] && j < 257){
          float v = __expf((acc[c][r] - mx[r]) * 0.125f) * inv_[r];
          __builtin_nontemporal_store(v, &out[rb + j]);
        }
      }
    }
  }
  __syncthreads();                                   // (2) kl dead -> vT live

  // ---- stage vT[e][j] from vreg prefetch (zero pads j=257..295)
  for (int i = tid; i < 64*19; i += 256){
    int row = i / 19, cc = (i % 19)*2 + 258;
    *(uint32_t*)&vT[row*296 + cc] = 0;
  }
  if (tid < 64) vT[tid*296 + 257] = 0;
  #pragma unroll
  for (int u = 0; u < 17; u++){
    int c = tid + u*256;
    if (c < 4112){
      int row = c >> 4, c4 = (c & 15) * 4;
      vT[(c4+0)*296 + row] = vreg[u].x;
      vT[(c4+1)*296 + row] = vreg[u].y;
      vT[(c4+2)*296 + row] = vreg[u].z;
      vT[(c4+3)*296 + row] = vreg[u].w;
    }
  }
  __syncthreads();                                   // (3) vT ready

  // ---- inner = P @ V via wave-local 16x32 P-chunks (no cross-wave barriers).
  // Fully unrolled with wave-uniform guard so acc[] indices are compile-time.
  const int nks = (t == 4) ? 9 : (2*t + 2);
  #pragma unroll
  for (int ks = 0; ks < 9; ks++){
    if (ks < nks){
      #pragma unroll
      for (int cc = 0; cc < 2; cc++){
        const int f = ks*2 + cc;
        #pragma unroll
        for (int r = 0; r < 4; r++){
          float val = (f < 17 && (f*16 + l16) < 257) ? acc[f][r] : 0.f;
          plw[(lq*4 + r)*40 + cc*16 + l16] = f2bf(val);
        }
      }
      short8 a = *(const short8*)&plw[l16*40 + lq*8];
      #pragma unroll
      for (int ni = 0; ni < 4; ni++){
        short8 bb = *(const short8*)&vT[(ni*16 + l16)*296 + ks*32 + lq*8];
        acc2[ni] = __builtin_amdgcn_mfma_f32_16x16x32_bf16(a, bb, acc2[ni], 0, 0, 0);
      }
    }
  }

  // ---- r = inner + cross: store pre-norm + GroupNorm partials
  float ls = 0.f, lss = 0.f;
  #pragma unroll
  for (int ni = 0; ni < 4; ni++)
    #pragma unroll
    for (int r = 0; r < 4; r++)
      if (rowok[r]){
        float v = acc2[ni][r];
        ls += v; lss += v*v;
        out[(size_t)(b*257 + gi[r])*512 + h*64 + ni*16 + l16] = v;
      }
  #pragma unroll
  for (int m = 1; m < 64; m <<= 1){ ls += __shfl_xor(ls, m, 64); lss += __shfl_xor(lss, m, 64); }
  if (lane == 0){ red[wave*2] = ls; red[wave*2 + 1] = lss; }
  __syncthreads();                                   // (4)
  if (tid == 0){
    partials[((size_t)bh*5 + t)*2 + 0] = red[0] + red[2] + red[4] + red[6];
    partials[((size_t)bh*5 + t)*2 + 1] = red[1] + red[3] + red[5] + red[7];
  }
}

// ---- Kernel D: GroupNorm finalize in place. grid(256) = (b,h) ----
__global__ __launch_bounds__(256) void norm_kernel(const float* __restrict__ partials,
                                                   const float* __restrict__ gnw,
                                                   const float* __restrict__ gnb,
                                                   float* __restrict__ out){
  const int bh = blockIdx.x, b = bh >> 3, h = bh & 7;
  float s = 0.f, s2 = 0.f;
  #pragma unroll
  for (int tt = 0; tt < 5; tt++){
    s  += partials[(bh*5 + tt)*2 + 0];
    s2 += partials[(bh*5 + tt)*2 + 1];
  }
  const float cnt = 257.f * 64.f;
  float mean = s / cnt;
  float var  = s2 / cnt - mean * mean;
  float isd  = rsqrtf(var + 1e-5f);
  float wsc  = gnw[h] * isd;
  float bia  = gnb[h] - mean * wsc;
  for (int idx = threadIdx.x; idx < 257*16; idx += 256){
    int n = idx >> 4, e4 = (idx & 15) * 4;
    size_t off = (size_t)(b*257 + n)*512 + h*64 + e4;
    float4 v = *(float4*)&out[off];
    v.x = v.x * wsc + bia; v.y = v.y * wsc + bia;
    v.z = v.z * wsc + bia; v.w = v.w * wsc + bia;
    *(float4*)&out[off] = v;
  }
}

extern "C" void kernel_launch(void* const* d_in, const int* in_sizes, int n_in,
                              void* d_out, int out_size, void* d_ws, size_t ws_size,
                              hipStream_t stream){
  (void)in_sizes; (void)n_in; (void)out_size; (void)ws_size;
  const float* x   = (const float*)d_in[0];
  const int*   msk = (const int*)d_in[1];
  const float* w   = (const float*)d_in[2];
  const float* pkv = (const float*)d_in[3];
  const float* gnw = (const float*)d_in[4];
  const float* gnb = (const float*)d_in[5];
  float* out = (float*)d_out;

  unsigned short* qkv = (unsigned short*)d_ws;                       // 25264128 B
  unsigned short* xb  = (unsigned short*)((char*)d_ws + 25264128);   // 8421376 B
  unsigned short* wb  = (unsigned short*)((char*)d_ws + 33685504);   // 1572864 B
  float* mnorm    = (float*)((char*)d_ws + 35258368);                // 32768 B
  float* partials = (float*)((char*)d_ws + 35291136);                // 10240 B

  hipLaunchKernelGGL(prep_kernel, dim3(32), dim3(256), 0, stream, msk, mnorm);
  hipLaunchKernelGGL(cvt_kernel, dim3(4880), dim3(256), 0, stream, x, w, xb, wb);
  hipLaunchKernelGGL(qkv_gemm, dim3(12, 65), dim3(256), 0, stream, xb, wb, qkv);
  hipLaunchKernelGGL(retention_kernel, dim3(5, 256), dim3(256), 49440, stream,
                     qkv, pkv, mnorm, out, partials);
  hipLaunchKernelGGL(norm_kernel, dim3(256), dim3(256), 0, stream, partials, gnw, gnb, out);
}

// Round 2
// 284.692 us; speedup vs baseline: 1.1133x; 1.0548x over previous
//
#include <hip/hip_runtime.h>
#include <stdint.h>

// Problem constants: B=32, H=8, N=257, D=64, DIM=512
#define WB_OFF   4210688ull
#define WA_OFF   21119232ull

typedef short short8 __attribute__((ext_vector_type(8)));
typedef float floatx4 __attribute__((ext_vector_type(4)));
typedef __attribute__((address_space(1))) const unsigned int gu32;
typedef __attribute__((address_space(3))) unsigned int lu32;

__device__ __forceinline__ unsigned short f2bf(float f){
  union { float f; uint32_t u; } v; v.f = f;
  uint32_t u = v.u;
  uint32_t r = (u + 0x7FFFu + ((u >> 16) & 1u)) >> 16;  // RNE
  return (unsigned short)r;
}

// ---- JAX Threefry-2x32 ----
__device__ __forceinline__ void threefry(uint32_t k0, uint32_t k1, uint32_t c0, uint32_t c1,
                                         uint32_t& o0, uint32_t& o1){
  const uint32_t ks2 = k0 ^ k1 ^ 0x1BD11BDAu;
  uint32_t x0 = c0 + k0, x1 = c1 + k1;
#define TF_R4(a,b,c,d) \
  x0+=x1; x1=(x1<<(a))|(x1>>(32-(a))); x1^=x0; \
  x0+=x1; x1=(x1<<(b))|(x1>>(32-(b))); x1^=x0; \
  x0+=x1; x1=(x1<<(c))|(x1>>(32-(c))); x1^=x0; \
  x0+=x1; x1=(x1<<(d))|(x1>>(32-(d))); x1^=x0;
  TF_R4(13,15,26,6)  x0+=k1;  x1+=ks2+1u;
  TF_R4(17,29,16,24) x0+=ks2; x1+=k0+2u;
  TF_R4(13,15,26,6)  x0+=k0;  x1+=k1+3u;
  TF_R4(17,29,16,24) x0+=k1;  x1+=ks2+4u;
  TF_R4(13,15,26,6)  x0+=ks2; x1+=k0+5u;
#undef TF_R4
  o0 = x0; o1 = x1;
}

// ---- Kernel A (fused): fp32->bf16 convert for x,w + prep (noise + mask norm).
// Blocks [0,4880) do the convert; blocks [4880,4912) do prep for b = blk-4880.
__global__ __launch_bounds__(256) void cvt_prep_kernel(const float* __restrict__ x,
                                                       const float* __restrict__ w,
                                                       unsigned short* __restrict__ xb,
                                                       unsigned short* __restrict__ wb,
                                                       const int* __restrict__ msk,
                                                       float* __restrict__ mnorm){
  __shared__ float sm[256];
  if (blockIdx.x < 4880){
    int i = blockIdx.x*256 + threadIdx.x;
    if (i < 1052672){
      float4 v = ((const float4*)x)[i];
      ushort4 o; o.x=f2bf(v.x); o.y=f2bf(v.y); o.z=f2bf(v.z); o.w=f2bf(v.w);
      ((ushort4*)xb)[i] = o;
    } else if (i < 1249280){
      int j = i - 1052672;
      float4 v = ((const float4*)w)[j];
      ushort4 o; o.x=f2bf(v.x); o.y=f2bf(v.y); o.z=f2bf(v.z); o.w=f2bf(v.w);
      ((ushort4*)wb)[j] = o;
    }
  } else {
    const int b = blockIdx.x - 4880, p = threadIdx.x;
    const int i = b*256 + p;
    uint32_t A0, A1, B0, B1;
    threefry(0u, 42u, 0u, 0u, A0, A1);   // k1
    threefry(0u, 42u, 0u, 1u, B0, B1);   // k2
    uint32_t h0, h1, l0, l1;
    threefry(A0, A1, 0u, (uint32_t)i, h0, h1);
    threefry(B0, B1, 0u, (uint32_t)i, l0, l1);
    uint32_t hb = h0 ^ h1, lb = l0 ^ l1;
    uint32_t off = ((hb % 127u) * 16u + (lb % 127u)) % 127u;
    int mv = msk[i];
    float m = (mv == 0) ? (float)(1u + off) : (float)mv;
    sm[p] = m; __syncthreads();
    for (int s = 128; s > 0; s >>= 1){
      if (p < s) sm[p] = fmaxf(sm[p], sm[p+s]);
      __syncthreads();
    }
    mnorm[i] = m / sm[0];
  }
}

// ---- Kernel B: QKV GEMM  qkv[8224,1536] = xb[8224,512] @ wb[1536,512]^T
// 128x128 tile, BK=64 (8 iters), global_load_lds + XOR col swizzle (conflict-free
// ds_read with unpadded lane-linear LDS). Coalesced C store via LDS. grid(12,65).
__global__ __launch_bounds__(256) void qkv_gemm(const unsigned short* __restrict__ xb,
                                                const unsigned short* __restrict__ wb,
                                                unsigned short* __restrict__ qkv){
  __shared__ unsigned short sm2[128*64*2 + 128*8];  // al/bl 32768B; c_lds [128][136] 34816B
  unsigned short* al = sm2;              // [128][64] lane-linear, col chunks XOR-swizzled
  unsigned short* bl = sm2 + 128*64;
  unsigned short* c_lds = sm2;           // [128][136] (reuse after K-loop)
  const int bn = blockIdx.x, bm = blockIdx.y;
  const int tid = threadIdx.x;
  const int wave = tid >> 6, lane = tid & 63;
  const int l16 = lane & 15, lq = lane >> 4;
  const int wm = (wave & 1) * 64, wn = (wave >> 1) * 64;
  const int row0 = tid >> 3;
  const int ccg = ((tid & 7) ^ (row0 & 7)) * 8;   // swizzled global col chunk
  const int sx = (l16 & 7);                        // compute-side swizzle key
  floatx4 acc[4][4] = {};
  for (int kk = 0; kk < 512; kk += 64){
    #pragma unroll
    for (int p = 0; p < 4; p++){
      int row = p*32 + row0;
      int gm = bm*128 + row; if (gm > 8223) gm = 8223;
      __builtin_amdgcn_global_load_lds((gu32*)&xb[(size_t)gm*512 + kk + ccg],
                                       (lu32*)&al[row*64 + (tid & 7)*8], 16, 0, 0);
      int gn = bn*128 + row;
      __builtin_amdgcn_global_load_lds((gu32*)&wb[(size_t)gn*512 + kk + ccg],
                                       (lu32*)&bl[row*64 + (tid & 7)*8], 16, 0, 0);
    }
    __syncthreads();
    #pragma unroll
    for (int ks = 0; ks < 2; ks++){
      short8 af[4], bf4[4];
      #pragma unroll
      for (int mi = 0; mi < 4; mi++){
        int ch = (ks*4 + lq) ^ sx;
        af[mi] = *(const short8*)&al[(wm + mi*16 + l16)*64 + ch*8];
      }
      #pragma unroll
      for (int ni = 0; ni < 4; ni++){
        int ch = (ks*4 + lq) ^ sx;
        bf4[ni] = *(const short8*)&bl[(wn + ni*16 + l16)*64 + ch*8];
      }
      #pragma unroll
      for (int mi = 0; mi < 4; mi++)
        #pragma unroll
        for (int ni = 0; ni < 4; ni++)
          acc[mi][ni] = __builtin_amdgcn_mfma_f32_16x16x32_bf16(af[mi], bf4[ni], acc[mi][ni], 0, 0, 0);
    }
    __syncthreads();
  }
  // epilogue: C tile -> LDS [128][136] -> coalesced 16B stores
  #pragma unroll
  for (int mi = 0; mi < 4; mi++)
    #pragma unroll
    for (int ni = 0; ni < 4; ni++)
      #pragma unroll
      for (int r = 0; r < 4; r++)
        c_lds[(wm + mi*16 + lq*4 + r)*136 + wn + ni*16 + l16] = f2bf(acc[mi][ni][r]);
  __syncthreads();
  for (int i = tid; i < 128*16; i += 256){
    int row = i >> 4, cc = (i & 15)*8;
    int gm = bm*128 + row;
    if (gm < 8224){
      ushort4 v0 = *(const ushort4*)&c_lds[row*136 + cc];
      ushort4 v1 = *(const ushort4*)&c_lds[row*136 + cc + 4];
      *(ushort4*)&qkv[(size_t)gm*1536 + bn*128 + cc] = v0;
      *(ushort4*)&qkv[(size_t)gm*1536 + bn*128 + cc + 4] = v1;
    }
  }
}

// ---- Kernel C: fused retention. grid(5, 256): x=row tile (64 rows), y=(b*8+h).
// v3: weight stores are plain CACHED scalar stores (A/B vs v2's nontemporal).
// Theory: nt bypasses L2 write-combining; row pitch 1028B => every 64B wave
// store span straddles sectors => ~1.87x write amplification (270MB vs 152MB
// ideal). Cached stores from the same wave are temporally adjacent per line,
// so L2 merges to full-line writebacks.
// LDS (dynamic 49440 B), 3 blocks/CU:
//   X [0,39168):   kl[272][72]  ->  vT[64][296]
//   Y [39168,48384): pkl[64][72] ->  plw (per-wave [16][40], 39168+wave*1280)
//   mn [48384,49408), red [49408,49440)
__global__ __launch_bounds__(256, 3) void retention_kernel(
    const unsigned short* __restrict__ qkv,
    const float* __restrict__ past_kv,
    const float* __restrict__ mnorm,
    float* __restrict__ out,
    float* __restrict__ partials){
  const int t  = blockIdx.x;
  const int bh = blockIdx.y;
  const int b = bh >> 3, h = bh & 7;
  const int tid = threadIdx.x;
  const int wave = tid >> 6, lane = tid & 63;
  const int l16 = lane & 15, lq = lane >> 4;
  const int rw = wave * 16;

  extern __shared__ unsigned char smem[];
  unsigned short* kl  = (unsigned short*)smem;                    // [272][72]
  unsigned short* vT  = (unsigned short*)smem;                    // [64][296]
  unsigned short* pkl = (unsigned short*)(smem + 39168);          // [64][72]
  unsigned short* plw = (unsigned short*)(smem + 39168 + wave*1280); // [16][40]
  float* mn  = (float*)(smem + 48384);
  float* red = (float*)(smem + 49408);

  // ---- phase A: zero pads, then one batched global-load burst, then LDS writes
  {
    uint32_t* z = (uint32_t*)(kl + 257*72);
    for (int i = tid; i < 540; i += 256) z[i] = 0;
  }
  ushort4 kreg[17];
  #pragma unroll
  for (int u = 0; u < 17; u++){
    int c = tid + u*256;
    if (c < 4112){
      int row = c >> 4, c4 = (c & 15) * 4;
      kreg[u] = *(const ushort4*)&qkv[(size_t)(b*257 + row)*1536 + 512 + h*64 + c4];
    }
  }
  float4 preg[4];
  #pragma unroll
  for (int u = 0; u < 4; u++){
    int c = tid + u*256;
    int d = c >> 4, e4 = (c & 15) * 4;
    preg[u] = *(const float4*)&past_kv[(size_t)bh*4096 + d*64 + e4];
  }
  float mnv = mnorm[b*256 + tid];
  int giA = t*64 + rw + l16; if (giA > 256) giA = 256;
  short8 aq[2];
  aq[0] = *(const short8*)&qkv[(size_t)(b*257 + giA)*1536 + h*64 + lq*8];
  aq[1] = *(const short8*)&qkv[(size_t)(b*257 + giA)*1536 + h*64 + 32 + lq*8];
  // v prefetch: consumed only after softmax2 -> in flight across the whole
  // compute phase (raw barrier below does not drain vmcnt).
  ushort4 vreg[17];
  #pragma unroll
  for (int u = 0; u < 17; u++){
    int c = tid + u*256;
    if (c < 4112){
      int row = c >> 4, c4 = (c & 15) * 4;
      vreg[u] = *(const ushort4*)&qkv[(size_t)(b*257 + row)*1536 + 1024 + h*64 + c4];
    }
  }
  // LDS writes (counted vmcnt waits: start as soon as kreg/preg land)
  #pragma unroll
  for (int u = 0; u < 17; u++){
    int c = tid + u*256;
    if (c < 4112){
      int row = c >> 4, c4 = (c & 15) * 4;
      *(ushort4*)&kl[row*72 + c4] = kreg[u];
    }
  }
  #pragma unroll
  for (int u = 0; u < 4; u++){
    int c = tid + u*256;
    int d = c >> 4, e4 = (c & 15) * 4;
    pkl[(e4+0)*72 + d] = f2bf(0.125f * preg[u].x);
    pkl[(e4+1)*72 + d] = f2bf(0.125f * preg[u].y);
    pkl[(e4+2)*72 + d] = f2bf(0.125f * preg[u].z);
    pkl[(e4+3)*72 + d] = f2bf(0.125f * preg[u].w);
  }
  mn[tid] = mnv;
  // (1) raw barrier: LDS visibility only; vreg loads stay outstanding
  asm volatile("s_waitcnt lgkmcnt(0)" ::: "memory");
  __builtin_amdgcn_s_barrier();

  // ---- cross-retention: acc2 = q @ (0.125*past_kv)
  floatx4 acc2[4] = {};
  #pragma unroll
  for (int ks = 0; ks < 2; ks++)
    #pragma unroll
    for (int ni = 0; ni < 4; ni++){
      short8 bb = *(const short8*)&pkl[(ni*16 + l16)*72 + ks*32 + lq*8];
      acc2[ni] = __builtin_amdgcn_mfma_f32_16x16x32_bf16(aq[ks], bb, acc2[ni], 0, 0, 0);
    }

  // ---- S = 0.125 * q @ k^T
  floatx4 acc[17] = {};
  #pragma unroll
  for (int ks = 0; ks < 2; ks++)
    #pragma unroll
    for (int c = 0; c < 17; c++){
      short8 bb = *(const short8*)&kl[(c*16 + l16)*72 + ks*32 + lq*8];
      acc[c] = __builtin_amdgcn_mfma_f32_16x16x32_bf16(aq[ks], bb, acc[c], 0, 0, 0);
    }
  #pragma unroll
  for (int c = 0; c < 17; c++) acc[c] *= 0.125f;

  int gi[4]; bool rowok[4];
  #pragma unroll
  for (int r = 0; r < 4; r++){ gi[r] = t*64 + rw + lq*4 + r; rowok[r] = (gi[r] < 257); }

  float mx[4], sum_[4], inv_[4];

  // ================= softmax1 -> weights_before (direct cached stores) =================
  #pragma unroll
  for (int r = 0; r < 4; r++) mx[r] = -3.0e38f;
  #pragma unroll
  for (int c = 0; c < 17; c++){
    bool jok = (c < 16) || (l16 == 0);
    if (jok){
      #pragma unroll
      for (int r = 0; r < 4; r++) mx[r] = fmaxf(mx[r], acc[c][r]);
    }
  }
  #pragma unroll
  for (int m = 1; m < 16; m <<= 1)
    #pragma unroll
    for (int r = 0; r < 4; r++) mx[r] = fmaxf(mx[r], __shfl_xor(mx[r], m, 64));
  #pragma unroll
  for (int r = 0; r < 4; r++) sum_[r] = 0.f;
  #pragma unroll
  for (int c = 0; c < 17; c++){
    bool jok = (c < 16) || (l16 == 0);
    if (jok){
      #pragma unroll
      for (int r = 0; r < 4; r++) sum_[r] += __expf((acc[c][r] - mx[r]) * 0.125f);
    }
  }
  #pragma unroll
  for (int m = 1; m < 16; m <<= 1)
    #pragma unroll
    for (int r = 0; r < 4; r++) sum_[r] += __shfl_xor(sum_[r], m, 64);
  #pragma unroll
  for (int r = 0; r < 4; r++) inv_[r] = 1.0f / sum_[r];

  {
    const size_t gbase = WB_OFF + (size_t)bh*66049;
    #pragma unroll
    for (int r = 0; r < 4; r++){
      size_t rb = gbase + (size_t)gi[r]*257;
      #pragma unroll
      for (int c = 0; c < 17; c++){
        int j = c*16 + l16;
        if (rowok[r] && j < 257){
          float v = __expf((acc[c][r] - mx[r]) * 0.125f) * inv_[r];
          out[rb + j] = v;
        }
      }
    }
  }

  // ---- apply mask in registers
  #pragma unroll
  for (int c = 0; c < 17; c++){
    int j = c*16 + l16;
    #pragma unroll
    for (int r = 0; r < 4; r++){
      int ii = gi[r] > 256 ? 256 : gi[r];
      float mv;
      if (j > ii)       mv = 0.f;
      else if (j == ii) mv = 1.f;
      else if (j == 0)  mv = __expf(-5.f * (float)ii * (1.f/256.f));
      else              mv = mn[ii-1] * mn[j-1];
      acc[c][r] *= mv;
    }
  }

  // ================= softmax2 -> weights_after (direct cached stores) =================
  #pragma unroll
  for (int r = 0; r < 4; r++) mx[r] = -3.0e38f;
  #pragma unroll
  for (int c = 0; c < 17; c++){
    bool jok = (c < 16) || (l16 == 0);
    if (jok){
      #pragma unroll
      for (int r = 0; r < 4; r++) mx[r] = fmaxf(mx[r], acc[c][r]);
    }
  }
  #pragma unroll
  for (int m = 1; m < 16; m <<= 1)
    #pragma unroll
    for (int r = 0; r < 4; r++) mx[r] = fmaxf(mx[r], __shfl_xor(mx[r], m, 64));
  #pragma unroll
  for (int r = 0; r < 4; r++) sum_[r] = 0.f;
  #pragma unroll
  for (int c = 0; c < 17; c++){
    bool jok = (c < 16) || (l16 == 0);
    if (jok){
      #pragma unroll
      for (int r = 0; r < 4; r++) sum_[r] += __expf((acc[c][r] - mx[r]) * 0.125f);
    }
  }
  #pragma unroll
  for (int m = 1; m < 16; m <<= 1)
    #pragma unroll
    for (int r = 0; r < 4; r++) sum_[r] += __shfl_xor(sum_[r], m, 64);
  #pragma unroll
  for (int r = 0; r < 4; r++) inv_[r] = 1.0f / sum_[r];

  {
    const size_t gbase = WA_OFF + (size_t)bh*66049;
    #pragma unroll
    for (int r = 0; r < 4; r++){
      size_t rb = gbase + (size_t)gi[r]*257;
      #pragma unroll
      for (int c = 0; c < 17; c++){
        int j = c*16 + l16;
        if (rowok[r] && j < 257){
          float v = __expf((acc[c][r] - mx[r]) * 0.125f) * inv_[r];
          out[rb + j] = v;
        }
      }
    }
  }
  __syncthreads();                                   // (2) kl dead -> vT live

  // ---- stage vT[e][j] from vreg prefetch (zero pads j=257..295)
  for (int i = tid; i < 64*19; i += 256){
    int row = i / 19, cc = (i % 19)*2 + 258;
    *(uint32_t*)&vT[row*296 + cc] = 0;
  }
  if (tid < 64) vT[tid*296 + 257] = 0;
  #pragma unroll
  for (int u = 0; u < 17; u++){
    int c = tid + u*256;
    if (c < 4112){
      int row = c >> 4, c4 = (c & 15) * 4;
      vT[(c4+0)*296 + row] = vreg[u].x;
      vT[(c4+1)*296 + row] = vreg[u].y;
      vT[(c4+2)*296 + row] = vreg[u].z;
      vT[(c4+3)*296 + row] = vreg[u].w;
    }
  }
  __syncthreads();                                   // (3) vT ready

  // ---- inner = P @ V via wave-local 16x32 P-chunks (no cross-wave barriers).
  // Fully unrolled with wave-uniform guard so acc[] indices are compile-time.
  const int nks = (t == 4) ? 9 : (2*t + 2);
  #pragma unroll
  for (int ks = 0; ks < 9; ks++){
    if (ks < nks){
      #pragma unroll
      for (int cc = 0; cc < 2; cc++){
        const int f = ks*2 + cc;
        #pragma unroll
        for (int r = 0; r < 4; r++){
          float val = (f < 17 && (f*16 + l16) < 257) ? acc[f][r] : 0.f;
          plw[(lq*4 + r)*40 + cc*16 + l16] = f2bf(val);
        }
      }
      short8 a = *(const short8*)&plw[l16*40 + lq*8];
      #pragma unroll
      for (int ni = 0; ni < 4; ni++){
        short8 bb = *(const short8*)&vT[(ni*16 + l16)*296 + ks*32 + lq*8];
        acc2[ni] = __builtin_amdgcn_mfma_f32_16x16x32_bf16(a, bb, acc2[ni], 0, 0, 0);
      }
    }
  }

  // ---- r = inner + cross: store pre-norm + GroupNorm partials
  float ls = 0.f, lss = 0.f;
  #pragma unroll
  for (int ni = 0; ni < 4; ni++)
    #pragma unroll
    for (int r = 0; r < 4; r++)
      if (rowok[r]){
        float v = acc2[ni][r];
        ls += v; lss += v*v;
        out[(size_t)(b*257 + gi[r])*512 + h*64 + ni*16 + l16] = v;
      }
  #pragma unroll
  for (int m = 1; m < 64; m <<= 1){ ls += __shfl_xor(ls, m, 64); lss += __shfl_xor(lss, m, 64); }
  if (lane == 0){ red[wave*2] = ls; red[wave*2 + 1] = lss; }
  __syncthreads();                                   // (4)
  if (tid == 0){
    partials[((size_t)bh*5 + t)*2 + 0] = red[0] + red[2] + red[4] + red[6];
    partials[((size_t)bh*5 + t)*2 + 1] = red[1] + red[3] + red[5] + red[7];
  }
}

// ---- Kernel D: GroupNorm finalize in place. grid(256) = (b,h) ----
__global__ __launch_bounds__(256) void norm_kernel(const float* __restrict__ partials,
                                                   const float* __restrict__ gnw,
                                                   const float* __restrict__ gnb,
                                                   float* __restrict__ out){
  const int bh = blockIdx.x, b = bh >> 3, h = bh & 7;
  float s = 0.f, s2 = 0.f;
  #pragma unroll
  for (int tt = 0; tt < 5; tt++){
    s  += partials[(bh*5 + tt)*2 + 0];
    s2 += partials[(bh*5 + tt)*2 + 1];
  }
  const float cnt = 257.f * 64.f;
  float mean = s / cnt;
  float var  = s2 / cnt - mean * mean;
  float isd  = rsqrtf(var + 1e-5f);
  float wsc  = gnw[h] * isd;
  float bia  = gnb[h] - mean * wsc;
  for (int idx = threadIdx.x; idx < 257*16; idx += 256){
    int n = idx >> 4, e4 = (idx & 15) * 4;
    size_t off = (size_t)(b*257 + n)*512 + h*64 + e4;
    float4 v = *(float4*)&out[off];
    v.x = v.x * wsc + bia; v.y = v.y * wsc + bia;
    v.z = v.z * wsc + bia; v.w = v.w * wsc + bia;
    *(float4*)&out[off] = v;
  }
}

extern "C" void kernel_launch(void* const* d_in, const int* in_sizes, int n_in,
                              void* d_out, int out_size, void* d_ws, size_t ws_size,
                              hipStream_t stream){
  (void)in_sizes; (void)n_in; (void)out_size; (void)ws_size;
  const float* x   = (const float*)d_in[0];
  const int*   msk = (const int*)d_in[1];
  const float* w   = (const float*)d_in[2];
  const float* pkv = (const float*)d_in[3];
  const float* gnw = (const float*)d_in[4];
  const float* gnb = (const float*)d_in[5];
  float* out = (float*)d_out;

  unsigned short* qkv = (unsigned short*)d_ws;                       // 25264128 B
  unsigned short* xb  = (unsigned short*)((char*)d_ws + 25264128);   // 8421376 B
  unsigned short* wb  = (unsigned short*)((char*)d_ws + 33685504);   // 1572864 B
  float* mnorm    = (float*)((char*)d_ws + 35258368);                // 32768 B
  float* partials = (float*)((char*)d_ws + 35291136);                // 10240 B

  hipLaunchKernelGGL(cvt_prep_kernel, dim3(4912), dim3(256), 0, stream,
                     x, w, xb, wb, msk, mnorm);
  hipLaunchKernelGGL(qkv_gemm, dim3(12, 65), dim3(256), 0, stream, xb, wb, qkv);
  hipLaunchKernelGGL(retention_kernel, dim3(5, 256), dim3(256), 49440, stream,
                     qkv, pkv, mnorm, out, partials);
  hipLaunchKernelGGL(norm_kernel, dim3(256), dim3(256), 0, stream, partials, gnw, gnb, out);
}

// Round 3
// 265.088 us; speedup vs baseline: 1.1957x; 1.0740x over previous
//
#include <hip/hip_runtime.h>
#include <stdint.h>

// Problem constants: B=32, H=8, N=257, D=64, DIM=512
#define WB_OFF   4210688ull
#define WA_OFF   21119232ull

typedef short short8 __attribute__((ext_vector_type(8)));
typedef float floatx4 __attribute__((ext_vector_type(4)));
typedef __attribute__((address_space(1))) const unsigned int gu32;
typedef __attribute__((address_space(3))) unsigned int lu32;

// Raw workgroup barrier: LDS visibility only — does NOT drain vmcnt, so
// outstanding global stores/loads stay in flight across it (T14/T4).
// sched_barrier(0) fences both sides against compiler hoist/sink (rule #18).
#define RAW_BARRIER() do { \
  __builtin_amdgcn_sched_barrier(0); \
  asm volatile("s_waitcnt lgkmcnt(0)" ::: "memory"); \
  __builtin_amdgcn_s_barrier(); \
  __builtin_amdgcn_sched_barrier(0); \
} while(0)

__device__ __forceinline__ unsigned short f2bf(float f){
  union { float f; uint32_t u; } v; v.f = f;
  uint32_t u = v.u;
  uint32_t r = (u + 0x7FFFu + ((u >> 16) & 1u)) >> 16;  // RNE
  return (unsigned short)r;
}

// ---- JAX Threefry-2x32 ----
__device__ __forceinline__ void threefry(uint32_t k0, uint32_t k1, uint32_t c0, uint32_t c1,
                                         uint32_t& o0, uint32_t& o1){
  const uint32_t ks2 = k0 ^ k1 ^ 0x1BD11BDAu;
  uint32_t x0 = c0 + k0, x1 = c1 + k1;
#define TF_R4(a,b,c,d) \
  x0+=x1; x1=(x1<<(a))|(x1>>(32-(a))); x1^=x0; \
  x0+=x1; x1=(x1<<(b))|(x1>>(32-(b))); x1^=x0; \
  x0+=x1; x1=(x1<<(c))|(x1>>(32-(c))); x1^=x0; \
  x0+=x1; x1=(x1<<(d))|(x1>>(32-(d))); x1^=x0;
  TF_R4(13,15,26,6)  x0+=k1;  x1+=ks2+1u;
  TF_R4(17,29,16,24) x0+=ks2; x1+=k0+2u;
  TF_R4(13,15,26,6)  x0+=k0;  x1+=k1+3u;
  TF_R4(17,29,16,24) x0+=k1;  x1+=ks2+4u;
  TF_R4(13,15,26,6)  x0+=ks2; x1+=k0+5u;
#undef TF_R4
  o0 = x0; o1 = x1;
}

// ---- Kernel A (fused): fp32->bf16 convert for x,w + prep (noise + mask norm).
// Blocks [0,4880) do the convert; blocks [4880,4912) do prep for b = blk-4880.
__global__ __launch_bounds__(256) void cvt_prep_kernel(const float* __restrict__ x,
                                                       const float* __restrict__ w,
                                                       unsigned short* __restrict__ xb,
                                                       unsigned short* __restrict__ wb,
                                                       const int* __restrict__ msk,
                                                       float* __restrict__ mnorm){
  __shared__ float sm[256];
  if (blockIdx.x < 4880){
    int i = blockIdx.x*256 + threadIdx.x;
    if (i < 1052672){
      float4 v = ((const float4*)x)[i];
      ushort4 o; o.x=f2bf(v.x); o.y=f2bf(v.y); o.z=f2bf(v.z); o.w=f2bf(v.w);
      ((ushort4*)xb)[i] = o;
    } else if (i < 1249280){
      int j = i - 1052672;
      float4 v = ((const float4*)w)[j];
      ushort4 o; o.x=f2bf(v.x); o.y=f2bf(v.y); o.z=f2bf(v.z); o.w=f2bf(v.w);
      ((ushort4*)wb)[j] = o;
    }
  } else {
    const int b = blockIdx.x - 4880, p = threadIdx.x;
    const int i = b*256 + p;
    uint32_t A0, A1, B0, B1;
    threefry(0u, 42u, 0u, 0u, A0, A1);   // k1
    threefry(0u, 42u, 0u, 1u, B0, B1);   // k2
    uint32_t h0, h1, l0, l1;
    threefry(A0, A1, 0u, (uint32_t)i, h0, h1);
    threefry(B0, B1, 0u, (uint32_t)i, l0, l1);
    uint32_t hb = h0 ^ h1, lb = l0 ^ l1;
    uint32_t off = ((hb % 127u) * 16u + (lb % 127u)) % 127u;
    int mv = msk[i];
    float m = (mv == 0) ? (float)(1u + off) : (float)mv;
    sm[p] = m; __syncthreads();
    for (int s = 128; s > 0; s >>= 1){
      if (p < s) sm[p] = fmaxf(sm[p], sm[p+s]);
      __syncthreads();
    }
    mnorm[i] = m / sm[0];
  }
}

// ---- Kernel B: QKV GEMM  qkv[8224,1536] = xb[8224,512] @ wb[1536,512]^T
// 128x128 tile, BK=64 (8 iters), global_load_lds + XOR col swizzle (conflict-free
// ds_read with unpadded lane-linear LDS). Coalesced C store via LDS. grid(12,65).
__global__ __launch_bounds__(256) void qkv_gemm(const unsigned short* __restrict__ xb,
                                                const unsigned short* __restrict__ wb,
                                                unsigned short* __restrict__ qkv){
  __shared__ unsigned short sm2[128*64*2 + 128*8];  // al/bl 32768B; c_lds [128][136] 34816B
  unsigned short* al = sm2;              // [128][64] lane-linear, col chunks XOR-swizzled
  unsigned short* bl = sm2 + 128*64;
  unsigned short* c_lds = sm2;           // [128][136] (reuse after K-loop)
  const int bn = blockIdx.x, bm = blockIdx.y;
  const int tid = threadIdx.x;
  const int wave = tid >> 6, lane = tid & 63;
  const int l16 = lane & 15, lq = lane >> 4;
  const int wm = (wave & 1) * 64, wn = (wave >> 1) * 64;
  const int row0 = tid >> 3;
  const int ccg = ((tid & 7) ^ (row0 & 7)) * 8;   // swizzled global col chunk
  const int sx = (l16 & 7);                        // compute-side swizzle key
  floatx4 acc[4][4] = {};
  for (int kk = 0; kk < 512; kk += 64){
    #pragma unroll
    for (int p = 0; p < 4; p++){
      int row = p*32 + row0;
      int gm = bm*128 + row; if (gm > 8223) gm = 8223;
      __builtin_amdgcn_global_load_lds((gu32*)&xb[(size_t)gm*512 + kk + ccg],
                                       (lu32*)&al[row*64 + (tid & 7)*8], 16, 0, 0);
      int gn = bn*128 + row;
      __builtin_amdgcn_global_load_lds((gu32*)&wb[(size_t)gn*512 + kk + ccg],
                                       (lu32*)&bl[row*64 + (tid & 7)*8], 16, 0, 0);
    }
    __syncthreads();
    #pragma unroll
    for (int ks = 0; ks < 2; ks++){
      short8 af[4], bf4[4];
      #pragma unroll
      for (int mi = 0; mi < 4; mi++){
        int ch = (ks*4 + lq) ^ sx;
        af[mi] = *(const short8*)&al[(wm + mi*16 + l16)*64 + ch*8];
      }
      #pragma unroll
      for (int ni = 0; ni < 4; ni++){
        int ch = (ks*4 + lq) ^ sx;
        bf4[ni] = *(const short8*)&bl[(wn + ni*16 + l16)*64 + ch*8];
      }
      #pragma unroll
      for (int mi = 0; mi < 4; mi++)
        #pragma unroll
        for (int ni = 0; ni < 4; ni++)
          acc[mi][ni] = __builtin_amdgcn_mfma_f32_16x16x32_bf16(af[mi], bf4[ni], acc[mi][ni], 0, 0, 0);
    }
    __syncthreads();
  }
  // epilogue: C tile -> LDS [128][136] -> coalesced 16B stores
  #pragma unroll
  for (int mi = 0; mi < 4; mi++)
    #pragma unroll
    for (int ni = 0; ni < 4; ni++)
      #pragma unroll
      for (int r = 0; r < 4; r++)
        c_lds[(wm + mi*16 + lq*4 + r)*136 + wn + ni*16 + l16] = f2bf(acc[mi][ni][r]);
  __syncthreads();
  for (int i = tid; i < 128*16; i += 256){
    int row = i >> 4, cc = (i & 15)*8;
    int gm = bm*128 + row;
    if (gm < 8224){
      ushort4 v0 = *(const ushort4*)&c_lds[row*136 + cc];
      ushort4 v1 = *(const ushort4*)&c_lds[row*136 + cc + 4];
      *(ushort4*)&qkv[(size_t)gm*1536 + bn*128 + cc] = v0;
      *(ushort4*)&qkv[(size_t)gm*1536 + bn*128 + cc + 4] = v1;
    }
  }
}

// ---- Kernel C: fused retention. grid(5, 256): x=row tile (64 rows), y=(b*8+h).
// v4 restructure: NO vmcnt drain anywhere on the critical path.
//  * phase order: load burst -> [rawbar] -> cross+S MFMA -> [rawbar, kl dead]
//    -> vT stage from vreg -> [rawbar] -> softmax1+nt-stores -> mask ->
//    softmax2+nt-stores -> PV (wave-local) -> prenorm stores -> [rawbar] -> partials.
//    Weight stores are issued AFTER the last vT barrier, so they retire in the
//    background under the PV MFMA phase; only kernel-end drains them.
//  * vT staging consumes vreg BEFORE any store is issued, keeping the in-order
//    counted vmcnt waits for vreg <= 17 (no forced drain).
//  * weight stores nontemporal (proven faster issue path; bytes don't bind).
// LDS (dynamic 49440 B), 3 blocks/CU:
//   X [0,39168):   kl[272][72]  ->  vT[64][296]
//   Y [39168,48384): pkl[64][72] ->  plw (per-wave [16][40], 39168+wave*1280)
//   mn [48384,49408), red [49408,49440)
__global__ __launch_bounds__(256, 3) void retention_kernel(
    const unsigned short* __restrict__ qkv,
    const float* __restrict__ past_kv,
    const float* __restrict__ mnorm,
    float* __restrict__ out,
    float* __restrict__ partials){
  const int t  = blockIdx.x;
  const int bh = blockIdx.y;
  const int b = bh >> 3, h = bh & 7;
  const int tid = threadIdx.x;
  const int wave = tid >> 6, lane = tid & 63;
  const int l16 = lane & 15, lq = lane >> 4;
  const int rw = wave * 16;

  extern __shared__ unsigned char smem[];
  unsigned short* kl  = (unsigned short*)smem;                    // [272][72]
  unsigned short* vT  = (unsigned short*)smem;                    // [64][296]
  unsigned short* pkl = (unsigned short*)(smem + 39168);          // [64][72]
  unsigned short* plw = (unsigned short*)(smem + 39168 + wave*1280); // [16][40]
  float* mn  = (float*)(smem + 48384);
  float* red = (float*)(smem + 49408);

  // ---- phase A: zero pads, then one batched global-load burst, then LDS writes
  {
    uint32_t* z = (uint32_t*)(kl + 257*72);
    for (int i = tid; i < 540; i += 256) z[i] = 0;
  }
  ushort4 kreg[17];
  #pragma unroll
  for (int u = 0; u < 17; u++){
    int c = tid + u*256;
    if (c < 4112){
      int row = c >> 4, c4 = (c & 15) * 4;
      kreg[u] = *(const ushort4*)&qkv[(size_t)(b*257 + row)*1536 + 512 + h*64 + c4];
    }
  }
  float4 preg[4];
  #pragma unroll
  for (int u = 0; u < 4; u++){
    int c = tid + u*256;
    int d = c >> 4, e4 = (c & 15) * 4;
    preg[u] = *(const float4*)&past_kv[(size_t)bh*4096 + d*64 + e4];
  }
  float mnv = mnorm[b*256 + tid];
  int giA = t*64 + rw + l16; if (giA > 256) giA = 256;
  short8 aq[2];
  aq[0] = *(const short8*)&qkv[(size_t)(b*257 + giA)*1536 + h*64 + lq*8];
  aq[1] = *(const short8*)&qkv[(size_t)(b*257 + giA)*1536 + h*64 + 32 + lq*8];
  // v prefetch: consumed at vT staging (after MFMA phase) -> in flight across
  // the MFMA phase; raw barriers never drain vmcnt.
  ushort4 vreg[17];
  #pragma unroll
  for (int u = 0; u < 17; u++){
    int c = tid + u*256;
    if (c < 4112){
      int row = c >> 4, c4 = (c & 15) * 4;
      vreg[u] = *(const ushort4*)&qkv[(size_t)(b*257 + row)*1536 + 1024 + h*64 + c4];
    }
  }
  // LDS writes (counted vmcnt waits: start as soon as kreg/preg land)
  #pragma unroll
  for (int u = 0; u < 17; u++){
    int c = tid + u*256;
    if (c < 4112){
      int row = c >> 4, c4 = (c & 15) * 4;
      *(ushort4*)&kl[row*72 + c4] = kreg[u];
    }
  }
  #pragma unroll
  for (int u = 0; u < 4; u++){
    int c = tid + u*256;
    int d = c >> 4, e4 = (c & 15) * 4;
    pkl[(e4+0)*72 + d] = f2bf(0.125f * preg[u].x);
    pkl[(e4+1)*72 + d] = f2bf(0.125f * preg[u].y);
    pkl[(e4+2)*72 + d] = f2bf(0.125f * preg[u].z);
    pkl[(e4+3)*72 + d] = f2bf(0.125f * preg[u].w);
  }
  mn[tid] = mnv;
  RAW_BARRIER();                                     // (1) kl/pkl/mn ready

  // ---- cross-retention: acc2 = q @ (0.125*past_kv)
  floatx4 acc2[4] = {};
  #pragma unroll
  for (int ks = 0; ks < 2; ks++)
    #pragma unroll
    for (int ni = 0; ni < 4; ni++){
      short8 bb = *(const short8*)&pkl[(ni*16 + l16)*72 + ks*32 + lq*8];
      acc2[ni] = __builtin_amdgcn_mfma_f32_16x16x32_bf16(aq[ks], bb, acc2[ni], 0, 0, 0);
    }

  // ---- S = 0.125 * q @ k^T
  floatx4 acc[17] = {};
  #pragma unroll
  for (int ks = 0; ks < 2; ks++)
    #pragma unroll
    for (int c = 0; c < 17; c++){
      short8 bb = *(const short8*)&kl[(c*16 + l16)*72 + ks*32 + lq*8];
      acc[c] = __builtin_amdgcn_mfma_f32_16x16x32_bf16(aq[ks], bb, acc[c], 0, 0, 0);
    }
  #pragma unroll
  for (int c = 0; c < 17; c++) acc[c] *= 0.125f;

  RAW_BARRIER();                                     // (2) kl/pkl dead -> vT live

  // ---- stage vT[e][j] from vreg prefetch (zero pads j=257..295)
  for (int i = tid; i < 64*19; i += 256){
    int row = i / 19, cc = (i % 19)*2 + 258;
    *(uint32_t*)&vT[row*296 + cc] = 0;
  }
  if (tid < 64) vT[tid*296 + 257] = 0;
  #pragma unroll
  for (int u = 0; u < 17; u++){
    int c = tid + u*256;
    if (c < 4112){
      int row = c >> 4, c4 = (c & 15) * 4;
      vT[(c4+0)*296 + row] = vreg[u].x;
      vT[(c4+1)*296 + row] = vreg[u].y;
      vT[(c4+2)*296 + row] = vreg[u].z;
      vT[(c4+3)*296 + row] = vreg[u].w;
    }
  }
  RAW_BARRIER();                                     // (3) vT ready; last barrier
                                                     // before kernel tail

  int gi[4]; bool rowok[4];
  #pragma unroll
  for (int r = 0; r < 4; r++){ gi[r] = t*64 + rw + lq*4 + r; rowok[r] = (gi[r] < 257); }

  float mx[4], sum_[4], inv_[4];

  // ================= softmax1 -> weights_before (direct nt stores) =================
  #pragma unroll
  for (int r = 0; r < 4; r++) mx[r] = -3.0e38f;
  #pragma unroll
  for (int c = 0; c < 17; c++){
    bool jok = (c < 16) || (l16 == 0);
    if (jok){
      #pragma unroll
      for (int r = 0; r < 4; r++) mx[r] = fmaxf(mx[r], acc[c][r]);
    }
  }
  #pragma unroll
  for (int m = 1; m < 16; m <<= 1)
    #pragma unroll
    for (int r = 0; r < 4; r++) mx[r] = fmaxf(mx[r], __shfl_xor(mx[r], m, 64));
  #pragma unroll
  for (int r = 0; r < 4; r++) sum_[r] = 0.f;
  #pragma unroll
  for (int c = 0; c < 17; c++){
    bool jok = (c < 16) || (l16 == 0);
    if (jok){
      #pragma unroll
      for (int r = 0; r < 4; r++) sum_[r] += __expf((acc[c][r] - mx[r]) * 0.125f);
    }
  }
  #pragma unroll
  for (int m = 1; m < 16; m <<= 1)
    #pragma unroll
    for (int r = 0; r < 4; r++) sum_[r] += __shfl_xor(sum_[r], m, 64);
  #pragma unroll
  for (int r = 0; r < 4; r++) inv_[r] = 1.0f / sum_[r];

  {
    const size_t gbase = WB_OFF + (size_t)bh*66049;
    #pragma unroll
    for (int r = 0; r < 4; r++){
      size_t rb = gbase + (size_t)gi[r]*257;
      #pragma unroll
      for (int c = 0; c < 17; c++){
        int j = c*16 + l16;
        if (rowok[r] && j < 257){
          float v = __expf((acc[c][r] - mx[r]) * 0.125f) * inv_[r];
          __builtin_nontemporal_store(v, &out[rb + j]);
        }
      }
    }
  }

  // ---- apply mask in registers
  #pragma unroll
  for (int c = 0; c < 17; c++){
    int j = c*16 + l16;
    #pragma unroll
    for (int r = 0; r < 4; r++){
      int ii = gi[r] > 256 ? 256 : gi[r];
      float mv;
      if (j > ii)       mv = 0.f;
      else if (j == ii) mv = 1.f;
      else if (j == 0)  mv = __expf(-5.f * (float)ii * (1.f/256.f));
      else              mv = mn[ii-1] * mn[j-1];
      acc[c][r] *= mv;
    }
  }

  // ================= softmax2 -> weights_after (direct nt stores) =================
  #pragma unroll
  for (int r = 0; r < 4; r++) mx[r] = -3.0e38f;
  #pragma unroll
  for (int c = 0; c < 17; c++){
    bool jok = (c < 16) || (l16 == 0);
    if (jok){
      #pragma unroll
      for (int r = 0; r < 4; r++) mx[r] = fmaxf(mx[r], acc[c][r]);
    }
  }
  #pragma unroll
  for (int m = 1; m < 16; m <<= 1)
    #pragma unroll
    for (int r = 0; r < 4; r++) mx[r] = fmaxf(mx[r], __shfl_xor(mx[r], m, 64));
  #pragma unroll
  for (int r = 0; r < 4; r++) sum_[r] = 0.f;
  #pragma unroll
  for (int c = 0; c < 17; c++){
    bool jok = (c < 16) || (l16 == 0);
    if (jok){
      #pragma unroll
      for (int r = 0; r < 4; r++) sum_[r] += __expf((acc[c][r] - mx[r]) * 0.125f);
    }
  }
  #pragma unroll
  for (int m = 1; m < 16; m <<= 1)
    #pragma unroll
    for (int r = 0; r < 4; r++) sum_[r] += __shfl_xor(sum_[r], m, 64);
  #pragma unroll
  for (int r = 0; r < 4; r++) inv_[r] = 1.0f / sum_[r];

  {
    const size_t gbase = WA_OFF + (size_t)bh*66049;
    #pragma unroll
    for (int r = 0; r < 4; r++){
      size_t rb = gbase + (size_t)gi[r]*257;
      #pragma unroll
      for (int c = 0; c < 17; c++){
        int j = c*16 + l16;
        if (rowok[r] && j < 257){
          float v = __expf((acc[c][r] - mx[r]) * 0.125f) * inv_[r];
          __builtin_nontemporal_store(v, &out[rb + j]);
        }
      }
    }
  }

  // ---- inner = P @ V via wave-local 16x32 P-chunks (no cross-wave barriers).
  // Fully unrolled with wave-uniform guard so acc[] indices are compile-time.
  const int nks = (t == 4) ? 9 : (2*t + 2);
  #pragma unroll
  for (int ks = 0; ks < 9; ks++){
    if (ks < nks){
      #pragma unroll
      for (int cc = 0; cc < 2; cc++){
        const int f = ks*2 + cc;
        #pragma unroll
        for (int r = 0; r < 4; r++){
          float val = (f < 17 && (f*16 + l16) < 257) ? acc[f][r] : 0.f;
          plw[(lq*4 + r)*40 + cc*16 + l16] = f2bf(val);
        }
      }
      short8 a = *(const short8*)&plw[l16*40 + lq*8];
      #pragma unroll
      for (int ni = 0; ni < 4; ni++){
        short8 bb = *(const short8*)&vT[(ni*16 + l16)*296 + ks*32 + lq*8];
        acc2[ni] = __builtin_amdgcn_mfma_f32_16x16x32_bf16(a, bb, acc2[ni], 0, 0, 0);
      }
    }
  }

  // ---- r = inner + cross: store pre-norm + GroupNorm partials
  float ls = 0.f, lss = 0.f;
  #pragma unroll
  for (int ni = 0; ni < 4; ni++)
    #pragma unroll
    for (int r = 0; r < 4; r++)
      if (rowok[r]){
        float v = acc2[ni][r];
        ls += v; lss += v*v;
        out[(size_t)(b*257 + gi[r])*512 + h*64 + ni*16 + l16] = v;
      }
  #pragma unroll
  for (int m = 1; m < 64; m <<= 1){ ls += __shfl_xor(ls, m, 64); lss += __shfl_xor(lss, m, 64); }
  if (lane == 0){ red[wave*2] = ls; red[wave*2 + 1] = lss; }
  RAW_BARRIER();                                     // (4) red ready (LDS only)
  if (tid == 0){
    partials[((size_t)bh*5 + t)*2 + 0] = red[0] + red[2] + red[4] + red[6];
    partials[((size_t)bh*5 + t)*2 + 1] = red[1] + red[3] + red[5] + red[7];
  }
}

// ---- Kernel D: GroupNorm finalize in place. grid(256) = (b,h) ----
__global__ __launch_bounds__(256) void norm_kernel(const float* __restrict__ partials,
                                                   const float* __restrict__ gnw,
                                                   const float* __restrict__ gnb,
                                                   float* __restrict__ out){
  const int bh = blockIdx.x, b = bh >> 3, h = bh & 7;
  float s = 0.f, s2 = 0.f;
  #pragma unroll
  for (int tt = 0; tt < 5; tt++){
    s  += partials[(bh*5 + tt)*2 + 0];
    s2 += partials[(bh*5 + tt)*2 + 1];
  }
  const float cnt = 257.f * 64.f;
  float mean = s / cnt;
  float var  = s2 / cnt - mean * mean;
  float isd  = rsqrtf(var + 1e-5f);
  float wsc  = gnw[h] * isd;
  float bia  = gnb[h] - mean * wsc;
  for (int idx = threadIdx.x; idx < 257*16; idx += 256){
    int n = idx >> 4, e4 = (idx & 15) * 4;
    size_t off = (size_t)(b*257 + n)*512 + h*64 + e4;
    float4 v = *(float4*)&out[off];
    v.x = v.x * wsc + bia; v.y = v.y * wsc + bia;
    v.z = v.z * wsc + bia; v.w = v.w * wsc + bia;
    *(float4*)&out[off] = v;
  }
}

extern "C" void kernel_launch(void* const* d_in, const int* in_sizes, int n_in,
                              void* d_out, int out_size, void* d_ws, size_t ws_size,
                              hipStream_t stream){
  (void)in_sizes; (void)n_in; (void)out_size; (void)ws_size;
  const float* x   = (const float*)d_in[0];
  const int*   msk = (const int*)d_in[1];
  const float* w   = (const float*)d_in[2];
  const float* pkv = (const float*)d_in[3];
  const float* gnw = (const float*)d_in[4];
  const float* gnb = (const float*)d_in[5];
  float* out = (float*)d_out;

  unsigned short* qkv = (unsigned short*)d_ws;                       // 25264128 B
  unsigned short* xb  = (unsigned short*)((char*)d_ws + 25264128);   // 8421376 B
  unsigned short* wb  = (unsigned short*)((char*)d_ws + 33685504);   // 1572864 B
  float* mnorm    = (float*)((char*)d_ws + 35258368);                // 32768 B
  float* partials = (float*)((char*)d_ws + 35291136);                // 10240 B

  hipLaunchKernelGGL(cvt_prep_kernel, dim3(4912), dim3(256), 0, stream,
                     x, w, xb, wb, msk, mnorm);
  hipLaunchKernelGGL(qkv_gemm, dim3(12, 65), dim3(256), 0, stream, xb, wb, qkv);
  hipLaunchKernelGGL(retention_kernel, dim3(5, 256), dim3(256), 49440, stream,
                     qkv, pkv, mnorm, out, partials);
  hipLaunchKernelGGL(norm_kernel, dim3(256), dim3(256), 0, stream, partials, gnw, gnb, out);
}